// Round 13
// baseline (52.872 us; speedup 1.0000x reference)
//
#include <hip/hip_runtime.h>
#include <hip/hip_fp16.h>

typedef _Float16 half8 __attribute__((ext_vector_type(8)));
typedef _Float16 half4v __attribute__((ext_vector_type(4)));
typedef float float4v __attribute__((ext_vector_type(4)));

#define E_DIM 300
#define KP 320               // padded K (10 MFMA k-steps of 32)
#define B_ 32
#define NROW_CDD 3200        // 32*5*20
#define NROW_HIS 32000       // 32*50*20

// ---------------- Kernel 1: gather + l2-normalize -> fp16 rows (K padded to 320) --------
__global__ __launch_bounds__(256) void gather_norm(const int* __restrict__ cand,
                                                   const int* __restrict__ clk,
                                                   const float* __restrict__ emb,
                                                   _Float16* __restrict__ outH)
{
    int row  = blockIdx.x * 4 + (threadIdx.x >> 6);
    int lane = threadIdx.x & 63;
    int tok = (row < NROW_CDD) ? cand[row] : clk[row - NROW_CDD];
    const float* e = emb + (long)tok * E_DIM;
    float v[5];
    float ss = 0.f;
#pragma unroll
    for (int j = 0; j < 5; ++j) {
        int idx = lane + j * 64;
        float x = (idx < E_DIM) ? e[idx] : 0.f;
        v[j] = x;
        ss += x * x;
    }
#pragma unroll
    for (int off = 32; off; off >>= 1) ss += __shfl_xor(ss, off);
    float scale = 1.0f / fmaxf(sqrtf(ss), 1e-12f);
    _Float16* o = outH + (long)row * KP;
#pragma unroll
    for (int j = 0; j < 5; ++j) {
        int idx = lane + j * 64;
        o[idx] = (_Float16)((idx < E_DIM) ? v[j] * scale : 0.f);
    }
}

// ---------------- Kernel 2: LDS-free 64x64 wave-tile sim GEMM ---------------------------
// One 64x64 output tile per wave (acc[4][4]); no LDS, no barriers. Per k-step: 8
// independent 16B loads then 16 MFMAs -> compiler software-pipelines freely.
// grid (8, 32): wave-tile wt = bx*4+wave in [0,32) = 2 mtiles x 16 ntiles.
// Total bytes: 1024 waves x 82 KB = 74 MB (A panels L2-hot: re-read 16x per b).
__global__ __launch_bounds__(256, 4) void sim_gemm(const _Float16* __restrict__ wsH,
                                                   _Float16* __restrict__ simW)
{
    int b = blockIdx.y;
    int tid = threadIdx.x;
    int wave = tid >> 6, lane = tid & 63;
    int g = lane >> 4, r16 = lane & 15;

    int wt = blockIdx.x * 4 + wave;      // 0..31
    int m = wt >> 4, n = wt & 15;        // m: 2 x 64 rows, n: 16 x 64 cols

    const char* gA = (const char*)(wsH + (size_t)b * 100 * KP);
    const char* gB = (const char*)(wsH + (size_t)(NROW_CDD + b * 1000) * KP);

    // clamped row pointers (dup rows computed but never stored)
    const char* pA[4];
    const char* pB[4];
#pragma unroll
    for (int i = 0; i < 4; ++i) {
        int rA = m * 64 + i * 16 + r16; if (rA > 99) rA = 99;
        pA[i] = gA + (size_t)rA * 640;
        int rB = n * 64 + i * 16 + r16; if (rB > 999) rB = 999;
        pB[i] = gB + (size_t)rB * 640;
    }

    float4v acc[4][4];
#pragma unroll
    for (int mm = 0; mm < 4; ++mm)
#pragma unroll
        for (int nn = 0; nn < 4; ++nn) acc[mm][nn] = (float4v){0.f, 0.f, 0.f, 0.f};

#pragma unroll
    for (int k = 0; k < 10; ++k) {
        half8 af[4], bf[4];
#pragma unroll
        for (int i = 0; i < 4; ++i) {
            af[i] = *(const half8*)(pA[i] + k * 64 + g * 16);
            bf[i] = *(const half8*)(pB[i] + k * 64 + g * 16);
        }
#pragma unroll
        for (int mm = 0; mm < 4; ++mm)
#pragma unroll
            for (int nn = 0; nn < 4; ++nn)
                acc[mm][nn] = __builtin_amdgcn_mfma_f32_16x16x32_f16(af[mm], bf[nn], acc[mm][nn], 0, 0, 0);
    }

    // C/D layout (validated r1-r12): col = lane&15 (B-row), row = (lane>>4)*4+j (A-row)
    size_t obase = (size_t)b * 100000;
#pragma unroll
    for (int mm = 0; mm < 4; ++mm) {
#pragma unroll
        for (int nn = 0; nn < 4; ++nn) {
            int col = n * 64 + nn * 16 + r16;
            if (col < 1000) {
#pragma unroll
                for (int j = 0; j < 4; ++j) {
                    int r = m * 64 + mm * 16 + g * 4 + j;
                    if (r < 100) simW[obase + (size_t)r * 1000 + col] = (_Float16)acc[mm][nn][j];
                }
            }
        }
    }
}

// ---------------- Kernel 3: gaussian kernels + log pooling, one block per sim row -------
// grid 3200, 256 threads (250 active: h=tid%50, kq=tid/50, 4 k's each). LDS 12.6 KB.
__global__ __launch_bounds__(256) void knrm_pool(const _Float16* __restrict__ simW,
                                                 const float* __restrict__ cpad,
                                                 const float* __restrict__ hpad,
                                                 const float* __restrict__ ltr_w,
                                                 float* __restrict__ rowsum)
{
    __shared__ float sS[50 * 21];
    __shared__ float mS[50 * 21];
    __shared__ float wS[1000];
    __shared__ float part[4];

    int row = blockIdx.x;            // (b*5+c)*20 + s
    int b = row / 100;
    int tid = threadIdx.x;

    if (tid < 250) {
        int p = tid * 4;
        half4v hv = *(const half4v*)(simW + (size_t)row * 1000 + p);
        float4v mv = *(const float4v*)(hpad + (size_t)b * 1000 + p);
        *(float4v*)&wS[p] = *(const float4v*)(ltr_w + p);
#pragma unroll
        for (int q = 0; q < 4; ++q) {
            int pq = p + q, h = pq / 20, t = pq - h * 20;
            sS[h * 21 + t] = (float)hv[q];
            mS[h * 21 + t] = mv[q];
        }
    }
    __syncthreads();

    float val = 0.f;
    if (tid < 250) {
        int h = tid % 50, kq = tid / 50;     // kq 0..4, k = kq*4+j
        float bj[4], cj[4];
        bool is19[4];
#pragma unroll
        for (int j = 0; j < 4; ++j) {
            float mu = -0.9f + 0.1f * (float)(kq * 4 + j);
            bj[j] = 100.0f * mu;
            cj[j] = -50.0f * mu * mu;
            is19[j] = (kq * 4 + j) == 19;
        }
        float psum0 = 0.f, psum1 = 0.f, psum2 = 0.f, psum3 = 0.f;
        const float* sp = sS + h * 21;
        const float* mp = mS + h * 21;
#pragma unroll 4
        for (int t = 0; t < 20; ++t) {
            float s  = sp[t];
            float mm = mp[t];
            float d  = s - 1.0f;
            float arg19 = -500000.0f * d * d;
            float a0 = is19[0] ? arg19 : fmaf(fmaf(-50.0f, s, bj[0]), s, cj[0]);
            float a1 = is19[1] ? arg19 : fmaf(fmaf(-50.0f, s, bj[1]), s, cj[1]);
            float a2 = is19[2] ? arg19 : fmaf(fmaf(-50.0f, s, bj[2]), s, cj[2]);
            float a3 = is19[3] ? arg19 : fmaf(fmaf(-50.0f, s, bj[3]), s, cj[3]);
            psum0 = fmaf(__expf(a0), mm, psum0);
            psum1 = fmaf(__expf(a1), mm, psum1);
            psum2 = fmaf(__expf(a2), mm, psum2);
            psum3 = fmaf(__expf(a3), mm, psum3);
        }
        const float* wp = wS + h * 20 + kq * 4;
        val  = __logf(fmaxf(psum0, 1e-10f)) * wp[0];
        val += __logf(fmaxf(psum1, 1e-10f)) * wp[1];
        val += __logf(fmaxf(psum2, 1e-10f)) * wp[2];
        val += __logf(fmaxf(psum3, 1e-10f)) * wp[3];
    }
#pragma unroll
    for (int off = 32; off; off >>= 1) val += __shfl_down(val, off);
    int wave = tid >> 6, lane = tid & 63;
    if (lane == 0) part[wave] = val;
    __syncthreads();
    if (tid == 0)
        rowsum[row] = (part[0] + part[1] + part[2] + part[3]) * 0.01f * cpad[row];
}

// ---------------- Kernel 4: sum rows per (b,c) + bias + log_softmax over C=5 ------------
__global__ __launch_bounds__(64) void finalize(const float* __restrict__ rowsum,
                                               const float* __restrict__ ltr_b,
                                               float* __restrict__ out)
{
    int b = blockIdx.x;
    int tid = threadIdx.x;
    __shared__ float sc[5];
    if (tid < 5) {
        float a = ltr_b[0];
        const float* rp = rowsum + (b * 5 + tid) * 20;
#pragma unroll
        for (int s = 0; s < 20; ++s) a += rp[s];
        sc[tid] = a;
    }
    __syncthreads();
    if (tid < 5) {
        float m = fmaxf(fmaxf(fmaxf(sc[0], sc[1]), fmaxf(sc[2], sc[3])), sc[4]);
        float sum = 0.f;
#pragma unroll
        for (int i = 0; i < 5; ++i) sum += __expf(sc[i] - m);
        out[b * 5 + tid] = sc[tid] - m - __logf(sum);
    }
}

extern "C" void kernel_launch(void* const* d_in, const int* in_sizes, int n_in,
                              void* d_out, int out_size, void* d_ws, size_t ws_size,
                              hipStream_t stream)
{
    const int*   cand = (const int*)d_in[0];
    const int*   clk  = (const int*)d_in[1];
    const float* cpad = (const float*)d_in[2];
    const float* hpad = (const float*)d_in[3];
    const float* emb  = (const float*)d_in[4];
    const float* lw   = (const float*)d_in[5];
    const float* lb   = (const float*)d_in[6];
    float* out = (float*)d_out;

    _Float16* wsH  = (_Float16*)d_ws;                                                   // 22.528 MB
    _Float16* simW = (_Float16*)((char*)d_ws + (size_t)(NROW_CDD + NROW_HIS) * KP * 2); // 6.4 MB
    float* rowsum  = (float*)((char*)simW + (size_t)B_ * 100 * 1000 * 2);               // 12.8 KB

    hipLaunchKernelGGL(gather_norm, dim3((NROW_CDD + NROW_HIS) / 4), dim3(256), 0, stream,
                       cand, clk, emb, wsH);
    hipLaunchKernelGGL(sim_gemm, dim3(8, B_), dim3(256), 0, stream, wsH, simW);
    hipLaunchKernelGGL(knrm_pool, dim3(NROW_CDD), dim3(256), 0, stream,
                       simW, cpad, hpad, lw, rowsum);
    hipLaunchKernelGGL(finalize, dim3(B_), dim3(64), 0, stream, rowsum, lb, out);
}